// Round 6
// baseline (154.234 us; speedup 1.0000x reference)
//
#include <hip/hip_runtime.h>

typedef __attribute__((ext_vector_type(8))) short short8;
typedef __attribute__((ext_vector_type(4))) float f32x4;

__device__ __forceinline__ float bf2f(unsigned short u) {
    union { unsigned int i; float f; } v; v.i = ((unsigned int)u) << 16; return v.f;
}
__device__ __forceinline__ unsigned short f2bf(float f) {
    union { float f; unsigned int i; } v; v.f = f;
    unsigned int r = v.i + 0x7fffu + ((v.i >> 16) & 1u);  // RNE
    return (unsigned short)(r >> 16);
}
__device__ __forceinline__ void gload16(const unsigned short* g, unsigned short* l) {
    __builtin_amdgcn_global_load_lds(
        (const __attribute__((address_space(1))) unsigned int*)g,
        (__attribute__((address_space(3))) unsigned int*)l, 16, 0, 0);
}

// ---------------------------------------------------------------------------
// 8-wave GEMM with one-phase fragment prefetch:
//   C[M][1024](bf16) = A[M][K](bf16) @ Bt[1024][K]^T(bf16) + bias
// BM=256. MODE 0: BN=256, 4 phases/K-tile (merged transform, M=16384).
//         MODE 1: BN=128, 2 phases/K-tile (language-selected Wg1, M=8192).
// Phase = { barrier; lgkmcnt(0); 16 MFMA (frags prefetched LAST phase);
//           stage piece; prefetch next phase's frags; [vmcnt]; barrier }.
// Stage schedule identical to the verified round-5 kernel; hazard rule:
// region read at phase r is re-staged only at phase >= r+2.
// ---------------------------------------------------------------------------
template<int K, int MODE>
__global__ __launch_bounds__(512, 2) void gemm8(
    const unsigned short* __restrict__ A,
    const unsigned short* __restrict__ Bta,
    const unsigned short* __restrict__ Btb,
    const float* __restrict__ biasa,
    const float* __restrict__ biasb,
    unsigned short* __restrict__ Cb,
    const int* __restrict__ lang)
{
    constexpr int BN   = (MODE == 0) ? 256 : 128;
    constexpr int NBLK = 1024 / BN;
    constexpr int NT   = K / 64;
    constexpr int NPH  = (MODE == 0) ? 4 : 2;
    constexpr int MPP  = 8 / NPH;               // m-frags per phase
    constexpr int NR   = (MODE == 0) ? 4 : 2;   // n-frags per wave
    constexpr int WNS  = BN / 4;

    __shared__ __align__(16) unsigned short As[2][256][64];
    __shared__ __align__(16) unsigned short Bs[2][BN][64];

    const int t = threadIdx.x;
    const int nwg = gridDim.x;                  // 256, multiple of 8
    const int bid = blockIdx.x;
    const int swz = (bid & 7) * (nwg >> 3) + (bid >> 3);
    const int gm0 = (swz / NBLK) * 256;
    const int gn0 = (swz % NBLK) * BN;

    const unsigned short* Bt;
    const float* bias;
    int sel = 0;
    if (MODE == 0) {
        sel = gm0 >> 13;
        Bt = sel ? Btb : Bta;
        bias = sel ? biasb : biasa;
    } else {
        const int l = lang[gm0 >> 9];
        Bt = Bta + (size_t)l * ((size_t)K * 1024);
        bias = biasa + l * 1024;
    }

    const int lane = t & 63, w = t >> 6;
    const int wm = w >> 2, wn = w & 3;          // 2M x 4N waves
    const int fr = lane & 15, g4 = lane >> 4, f7 = lane & 7;

    const int sr  = t >> 3;                     // 0..63
    const int gsw = ((t & 7) ^ (sr & 7)) * 8;   // pre-swizzled global col
    const int lc  = (t & 7) * 8;                // linear LDS col
    const unsigned short* agb = A  + (size_t)(gm0 + sr) * K + gsw;
    const unsigned short* bgb = Bt + (size_t)(gn0 + sr) * K + gsw;

    f32x4 acc[8][NR];
#pragma unroll
    for (int m = 0; m < 8; ++m)
#pragma unroll
        for (int n = 0; n < NR; ++n)
            acc[m][n] = (f32x4){0.f, 0.f, 0.f, 0.f};

    auto stA = [&](int buf, int h, int kb) {
#pragma unroll
        for (int j = 0; j < 2; ++j)
            gload16(agb + (size_t)(j * 128 + h * 64) * K + kb,
                    &As[buf][h * 128 + j * 64 + sr][lc]);
    };
    auto stB = [&](int buf, int h, int kb) {
#pragma unroll
        for (int j = 0; j < 2; ++j)
            gload16(bgb + (size_t)(h * 128 + j * 64) * K + kb,
                    &Bs[buf][h * 128 + j * 64 + sr][lc]);
    };

    short8 afP[MPP][2], afQ[MPP][2], bf_[NR][2];

#define RDA(Q, AF, BUF)                                                        \
    _Pragma("unroll")                                                          \
    for (int i = 0; i < MPP; ++i) {                                            \
        const int mf = (Q) * MPP + i;                                          \
        const int row = (mf >> 2) * 128 + wm * 64 + (mf & 3) * 16 + fr;        \
        _Pragma("unroll")                                                      \
        for (int kk = 0; kk < 2; ++kk)                                         \
            AF[i][kk] = *(const short8*)&As[BUF][row][((kk * 4 + g4) ^ f7) * 8];\
    }
#define RDB(BUF)                                                               \
    _Pragma("unroll")                                                          \
    for (int n = 0; n < NR; ++n) {                                             \
        const int row = wn * WNS + n * 16 + fr;                                \
        _Pragma("unroll")                                                      \
        for (int kk = 0; kk < 2; ++kk)                                         \
            bf_[n][kk] = *(const short8*)&Bs[BUF][row][((kk * 4 + g4) ^ f7) * 8];\
    }
#define MFMA16(Q, AF)                                                          \
    __builtin_amdgcn_s_setprio(1);                                             \
    _Pragma("unroll")                                                          \
    for (int kk = 0; kk < 2; ++kk)                                             \
        _Pragma("unroll")                                                      \
        for (int i = 0; i < MPP; ++i)                                          \
            _Pragma("unroll")                                                  \
            for (int n = 0; n < NR; ++n)                                       \
                acc[(Q) * MPP + i][n] = __builtin_amdgcn_mfma_f32_16x16x32_bf16(\
                    AF[i][kk], bf_[n][kk], acc[(Q) * MPP + i][n], 0, 0, 0);    \
    __builtin_amdgcn_s_setprio(0);
#define VM(n) asm volatile("s_waitcnt vmcnt(%0)" :: "i"(n) : "memory")
#define PH_TOP() __builtin_amdgcn_sched_barrier(0); __builtin_amdgcn_s_barrier(); \
                 asm volatile("s_waitcnt lgkmcnt(0)" ::: "memory");               \
                 __builtin_amdgcn_sched_barrier(0)
#define PH_BOT() __builtin_amdgcn_sched_barrier(0); __builtin_amdgcn_s_barrier()

    // ---- prologue: stage tile0 full + tile1 partial; prefetch p0 frags ----
    if (MODE == 0) {
        stB(0, 0, 0); stB(0, 1, 0); stA(0, 0, 0); stA(0, 1, 0);
        stB(1, 0, 64); stB(1, 1, 64); stA(1, 0, 64);
        VM(6);                                   // tile0 landed
    } else {
        stB(0, 0, 0); stA(0, 0, 0); stA(0, 1, 0);
        stB(1, 0, 64); stA(1, 0, 64);
        VM(4);
    }
    __builtin_amdgcn_s_barrier();
    RDB(0);
    RDA(0, afP, 0);

    for (int u = 0; u < NT; ++u) {
        const int c = u & 1, o = c ^ 1;
        const int kb1 = (u + 1) * 64, kb2 = (u + 2) * 64;
        const bool s1 = (u + 1 < NT), s2 = (u + 2 < NT);

        if (MODE == 0) {
            // ---- p0 ----
            PH_TOP();
            MFMA16(0, afP);
            if (s1) stA(o, 1, kb1);
            RDA(1, afQ, c);
            if (s1) { VM(8); } else { VM(0); }
            PH_BOT();
            // ---- p1 ----
            PH_TOP();
            MFMA16(1, afQ);
            if (s2) stB(c, 0, kb2);
            RDA(2, afP, c);
            PH_BOT();
            // ---- p2 ----
            PH_TOP();
            MFMA16(2, afP);
            if (s2) stB(c, 1, kb2);
            RDA(3, afQ, c);
            if (s2) { VM(6); } else if (s1) { VM(2); } else { VM(0); }
            PH_BOT();
            // ---- p3 ----
            PH_TOP();
            MFMA16(3, afQ);
            if (s2) stA(c, 0, kb2);
            if (s1) { RDB(o); RDA(0, afP, o); }
            PH_BOT();
        } else {
            // ---- p0 ----
            PH_TOP();
            MFMA16(0, afP);
            if (s1) stA(o, 1, kb1);
            RDA(1, afQ, c);
            if (s1) { VM(2); } else { VM(0); }
            PH_BOT();
            // ---- p1 ----
            PH_TOP();
            MFMA16(1, afQ);
            if (s2) { stB(c, 0, kb2); stA(c, 0, kb2); }
            if (s1) { RDB(o); RDA(0, afP, o); }
            if (s2) { VM(4); } else { VM(0); }
            PH_BOT();
        }
    }

    // epilogue: D mapping col=lane&15, row=(lane>>4)*4+reg; bf16 store
    const int fq = lane >> 4;
    const size_t pitch  = (MODE == 0) ? 2048 : 1024;
    const size_t coloff = (MODE == 0) ? (size_t)sel * 1024 : 0;
    const int rbase = (MODE == 0) ? (gm0 & 8191) : gm0;
#pragma unroll
    for (int n = 0; n < NR; ++n) {
        const int col = gn0 + wn * WNS + n * 16 + fr;
        const float bv = bias[col];
#pragma unroll
        for (int m = 0; m < 8; ++m) {
            const int row0 = rbase + wm * 128 + m * 16 + fq * 4;
#pragma unroll
            for (int r = 0; r < 4; ++r)
                Cb[(size_t)(row0 + r) * pitch + coloff + col] = f2bf(acc[m][n][r] + bv);
        }
    }
#undef RDA
#undef RDB
#undef MFMA16
#undef VM
#undef PH_TOP
#undef PH_BOT
}

// W [K][N] f32 -> Wt [N][K] bf16 (per blockIdx.z slab)
__global__ __launch_bounds__(256) void wt_bf16(
    const float* __restrict__ W, unsigned short* __restrict__ Wt, int K, int N)
{
    __shared__ float tile[32][33];
    W  += (size_t)blockIdx.z * K * N;
    Wt += (size_t)blockIdx.z * K * N;
    const int n0 = blockIdx.x * 32, k0 = blockIdx.y * 32;
    const int x = threadIdx.x & 31, y = threadIdx.x >> 5;
#pragma unroll
    for (int i = 0; i < 4; ++i)
        tile[y + 8 * i][x] = W[(size_t)(k0 + y + 8 * i) * N + n0 + x];
    __syncthreads();
#pragma unroll
    for (int i = 0; i < 4; ++i)
        Wt[(size_t)(n0 + y + 8 * i) * K + k0 + x] = f2bf(tile[x][y + 8 * i]);
}

// f32 -> bf16 elementwise (2048 elems / block)
__global__ __launch_bounds__(256) void conv_bf16(
    const float* __restrict__ in, unsigned short* __restrict__ out)
{
    const size_t i = ((size_t)blockIdx.x * 256 + threadIdx.x) * 8;
    const float4 a = ((const float4*)(in + i))[0];
    const float4 b = ((const float4*)(in + i))[1];
    ushort4 u, v;
    u.x = f2bf(a.x); u.y = f2bf(a.y); u.z = f2bf(a.z); u.w = f2bf(a.w);
    v.x = f2bf(b.x); v.y = f2bf(b.y); v.z = f2bf(b.z); v.w = f2bf(b.w);
    *(ushort4*)(out + i)     = u;
    *(ushort4*)(out + i + 4) = v;
}

// in-place LN(1024)+ReLU on combined halves (bf16). grid 16384: r=b>>1, half=b&1
__global__ __launch_bounds__(256) void ln_relu_c(
    unsigned short* __restrict__ comb,
    const float* __restrict__ gn, const float* __restrict__ bn,
    const float* __restrict__ gt, const float* __restrict__ btp)
{
    const int b = blockIdx.x, t = threadIdx.x;
    const int r = b >> 1, half = b & 1;
    unsigned short* p = comb + (size_t)r * 2048 + half * 1024 + t * 4;
    ushort4 u = *(const ushort4*)p;
    const float x0 = bf2f(u.x), x1 = bf2f(u.y), x2 = bf2f(u.z), x3 = bf2f(u.w);
    float s1 = x0 + x1 + x2 + x3;
    float s2 = x0 * x0 + x1 * x1 + x2 * x2 + x3 * x3;
#pragma unroll
    for (int off = 32; off > 0; off >>= 1) {
        s1 += __shfl_down(s1, off);
        s2 += __shfl_down(s2, off);
    }
    __shared__ float red[8];
    const int wid = t >> 6;
    if ((t & 63) == 0) { red[wid] = s1; red[4 + wid] = s2; }
    __syncthreads();
    s1 = red[0] + red[1] + red[2] + red[3];
    s2 = red[4] + red[5] + red[6] + red[7];
    const float mean = s1 * (1.0f / 1024.0f);
    const float var = fmaxf(s2 * (1.0f / 1024.0f) - mean * mean, 0.0f);
    const float rstd = rsqrtf(var + 1e-5f);
    const float* G  = half ? gt : gn;
    const float* Be = half ? btp : bn;
    const float4 g  = ((const float4*)G)[t];
    const float4 be = ((const float4*)Be)[t];
    u.x = f2bf(fmaxf((x0 - mean) * rstd * g.x + be.x, 0.0f));
    u.y = f2bf(fmaxf((x1 - mean) * rstd * g.y + be.y, 0.0f));
    u.z = f2bf(fmaxf((x2 - mean) * rstd * g.z + be.z, 0.0f));
    u.w = f2bf(fmaxf((x3 - mean) * rstd * g.w + be.w, 0.0f));
    *(ushort4*)p = u;
}

// Fused: LN(1024)+ReLU (lang gamma/beta) -> gate dots -> sigmoid -> scale -> f32 out
__global__ __launch_bounds__(256) void ln_gate(
    const unsigned short* __restrict__ preln, const unsigned short* __restrict__ comb,
    const float* __restrict__ gg, const float* __restrict__ bgb,
    const float* __restrict__ Wg2, const float* __restrict__ bg2,
    const int* __restrict__ lang,
    float* __restrict__ outN, float* __restrict__ outT)
{
    const int r = blockIdx.x, t = threadIdx.x;
    const int l = lang[r >> 9];
    const ushort4 u = *(const ushort4*)(preln + (size_t)r * 1024 + t * 4);
    const float x0 = bf2f(u.x), x1 = bf2f(u.y), x2 = bf2f(u.z), x3 = bf2f(u.w);
    float s1 = x0 + x1 + x2 + x3;
    float s2 = x0 * x0 + x1 * x1 + x2 * x2 + x3 * x3;
#pragma unroll
    for (int off = 32; off > 0; off >>= 1) {
        s1 += __shfl_down(s1, off);
        s2 += __shfl_down(s2, off);
    }
    __shared__ float red[8];
    const int wid = t >> 6;
    if ((t & 63) == 0) { red[wid] = s1; red[4 + wid] = s2; }
    __syncthreads();
    s1 = red[0] + red[1] + red[2] + red[3];
    s2 = red[4] + red[5] + red[6] + red[7];
    const float mean = s1 * (1.0f / 1024.0f);
    const float var = fmaxf(s2 * (1.0f / 1024.0f) - mean * mean, 0.0f);
    const float rstd = rsqrtf(var + 1e-5f);
    const float4 g  = ((const float4*)(gg + l * 1024))[t];
    const float4 be = ((const float4*)(bgb + l * 1024))[t];
    const float h0 = fmaxf((x0 - mean) * rstd * g.x + be.x, 0.0f);
    const float h1 = fmaxf((x1 - mean) * rstd * g.y + be.y, 0.0f);
    const float h2 = fmaxf((x2 - mean) * rstd * g.z + be.z, 0.0f);
    const float h3 = fmaxf((x3 - mean) * rstd * g.w + be.w, 0.0f);
    const float4* W = (const float4*)(Wg2 + (size_t)l * 2048);
    const float4 wa = W[t * 2], wb = W[t * 2 + 1];
    float d0 = h0 * wa.x + h1 * wa.z + h2 * wb.x + h3 * wb.z;
    float d1 = h0 * wa.y + h1 * wa.w + h2 * wb.y + h3 * wb.w;
#pragma unroll
    for (int off = 32; off > 0; off >>= 1) {
        d0 += __shfl_down(d0, off);
        d1 += __shfl_down(d1, off);
    }
    __syncthreads();
    if ((t & 63) == 0) { red[wid] = d0; red[4 + wid] = d1; }
    __syncthreads();
    d0 = red[0] + red[1] + red[2] + red[3] + bg2[l * 2 + 0];
    d1 = red[4] + red[5] + red[6] + red[7] + bg2[l * 2 + 1];
    const float g0 = 1.0f / (1.0f + __expf(-d0));
    const float g1 = 1.0f / (1.0f + __expf(-d1));
    const ushort4 cn = *(const ushort4*)(comb + (size_t)r * 2048 + t * 4);
    const ushort4 ct = *(const ushort4*)(comb + (size_t)r * 2048 + 1024 + t * 4);
    float4 a, b;
    a.x = bf2f(cn.x) * g0; a.y = bf2f(cn.y) * g0; a.z = bf2f(cn.z) * g0; a.w = bf2f(cn.w) * g0;
    b.x = bf2f(ct.x) * g1; b.y = bf2f(ct.y) * g1; b.z = bf2f(ct.z) * g1; b.w = bf2f(ct.w) * g1;
    ((float4*)(outN + (size_t)r * 1024))[t] = a;
    ((float4*)(outT + (size_t)r * 1024))[t] = b;
}

extern "C" void kernel_launch(void* const* d_in, const int* in_sizes, int n_in,
                              void* d_out, int out_size, void* d_ws, size_t ws_size,
                              hipStream_t stream)
{
    const float* ner    = (const float*)d_in[0];
    const float* top    = (const float*)d_in[1];
    const int*   lang   = (const int*)d_in[2];
    const float* W_ner  = (const float*)d_in[3];
    const float* b_ner  = (const float*)d_in[4];
    const float* g_ner  = (const float*)d_in[5];
    const float* be_ner = (const float*)d_in[6];
    const float* W_top  = (const float*)d_in[7];
    const float* b_top  = (const float*)d_in[8];
    const float* g_top  = (const float*)d_in[9];
    const float* be_top = (const float*)d_in[10];
    const float* Wg1    = (const float*)d_in[11];
    const float* bg1    = (const float*)d_in[12];
    const float* gg     = (const float*)d_in[13];
    const float* bgb    = (const float*)d_in[14];
    const float* Wg2    = (const float*)d_in[15];
    const float* bg2    = (const float*)d_in[16];

    float* out  = (float*)d_out;
    float* outN = out;
    float* outT = out + 8388608;

    // ws layout (~80 MB): combined | actb (later preln2) | Wg1t
    char* ws = (char*)d_ws;
    unsigned short* combined = (unsigned short*)ws;                 // [8192][2048] bf16, 32MB
    unsigned short* actb     = (unsigned short*)(ws + 33554432);    // [16384][768] bf16, 24MB
    unsigned short* preln2   = (unsigned short*)(ws + 33554432);    // [8192][1024] bf16 overlays actb
    unsigned short* Wg1t     = (unsigned short*)(ws + 58720256);    // [5][1024][2048] bf16, 20MB
    unsigned short* W_nert   = (unsigned short*)outT;               // [1024][768] bf16 (d_out scratch)
    unsigned short* W_topt   = W_nert + 786432;                     // [1024][768]

    // weight prep: f32 [K][N] -> bf16 [N][K]
    wt_bf16<<<dim3(32, 24, 1), 256, 0, stream>>>(W_ner, W_nert, 768, 1024);
    wt_bf16<<<dim3(32, 24, 1), 256, 0, stream>>>(W_top, W_topt, 768, 1024);
    wt_bf16<<<dim3(32, 64, 5), 256, 0, stream>>>(Wg1, Wg1t, 2048, 1024);

    // activations f32 -> bf16, concatenated on M
    conv_bf16<<<3072, 256, 0, stream>>>(ner, actb);
    conv_bf16<<<3072, 256, 0, stream>>>(top, actb + 6291456);

    // merged shared-transform GEMM: [16384][768] -> combined pre-LN (bf16)
    gemm8<768, 0><<<256, 512, 0, stream>>>(
        actb, W_nert, W_topt, b_ner, b_top, combined, nullptr);
    ln_relu_c<<<16384, 256, 0, stream>>>(combined, g_ner, be_ner, g_top, be_top);

    // gate MLP first layer (language-selected): combined @ Wg1t[l] -> preln2
    gemm8<2048, 1><<<256, 512, 0, stream>>>(
        combined, Wg1t, nullptr, bg1, nullptr, preln2, lang);

    // fused LN2 + gate dots + sigmoid + output scaling
    ln_gate<<<8192, 256, 0, stream>>>(preln2, combined, gg, bgb, Wg2, bg2, lang, outN, outT);
}

// Round 8
// 152.802 us; speedup vs baseline: 1.0094x; 1.0094x over previous
//
#include <hip/hip_runtime.h>

typedef __attribute__((ext_vector_type(8))) short short8;
typedef __attribute__((ext_vector_type(4))) float f32x4;

__device__ __forceinline__ float bf2f(unsigned short u) {
    union { unsigned int i; float f; } v; v.i = ((unsigned int)u) << 16; return v.f;
}
__device__ __forceinline__ unsigned short f2bf(float f) {
    union { float f; unsigned int i; } v; v.f = f;
    unsigned int r = v.i + 0x7fffu + ((v.i >> 16) & 1u);  // RNE
    return (unsigned short)(r >> 16);
}
__device__ __forceinline__ void gload16(const unsigned short* g, unsigned short* l) {
    __builtin_amdgcn_global_load_lds(
        (const __attribute__((address_space(1))) unsigned int*)g,
        (__attribute__((address_space(3))) unsigned int*)l, 16, 0, 0);
}

// ---------------------------------------------------------------------------
// 128x128 GEMM, BK=32, 4 waves, 2-deep counted-vmcnt pipeline, 32KB LDS ->
// 4 blocks/CU (launch_bounds(256,4)).
// Staging is LANE-LINEAR (rule #21): thread t -> LDS byte offset t*16
// (row=t>>2, slot=t&3); the XOR key (r&3)^((r>>2)&3) is applied to the
// GLOBAL source column and inverted on the ds_read side. Read-side 16B-slot
// index (r&1)*4 + (g4^key) is uniform over 0..7 -> conflict-free.
// MODE 0: merged shared transform (M=16384, sel by row half, bf16 out p2048).
// MODE 1: gate GEMM, language-selected B, 2-way K-split (1024 blocks),
//         f32 partial out to Cb + ks*8M floats; bias only on ks=0.
// ---------------------------------------------------------------------------
template<int KPITCH, int KLEN, int MODE>
__global__ __launch_bounds__(256, 4) void gemm_ks(
    const unsigned short* __restrict__ A,
    const unsigned short* __restrict__ Bta,
    const unsigned short* __restrict__ Btb,
    const float* __restrict__ biasa,
    const float* __restrict__ biasb,
    void* __restrict__ Cbv,
    const int* __restrict__ lang)
{
    constexpr int NT = KLEN / 32;
    __shared__ __align__(16) unsigned short As[2][128][32];
    __shared__ __align__(16) unsigned short Bs[2][128][32];

    const int t = threadIdx.x;
    const int nwg = gridDim.x;                  // 1024, multiple of 8
    const int bid = blockIdx.x;
    const int swz = (bid & 7) * (nwg >> 3) + (bid >> 3);

    int gm0, gn0, koff = 0, sel = 0;
    const unsigned short* Bt;
    const float* bias;
    if (MODE == 0) {
        gm0 = (swz >> 3) * 128;                 // 0..127 m-blocks (M=16384)
        gn0 = (swz & 7) * 128;
        sel = gm0 >> 13;
        Bt = sel ? Btb : Bta;
        bias = sel ? biasb : biasa;
    } else {
        const int ks = swz & 1, rem = swz >> 1; // pair (2k,2k+1): same (m,n), same XCD
        gm0 = (rem >> 3) * 128;
        gn0 = (rem & 7) * 128;
        koff = ks * KLEN;
        const int l = lang[gm0 >> 9];
        Bt = Bta + (size_t)l * ((size_t)KPITCH * 1024);
        bias = ks ? nullptr : (biasa + l * 1024);
    }

    const int lane = t & 63, w = t >> 6;
    const int wm = w >> 1, wn = w & 1;          // 2x2 waves, 64x64 each
    const int fr = lane & 15, g4 = lane >> 4;
    const int fkey = (fr & 3) ^ ((fr >> 2) & 3);
    const int csw = (g4 ^ fkey) * 8;            // swizzled frag col (elements)

    // staging: thread t -> row sr=t>>2, slot=t&3 -> LDS byte offset t*16 (lane-linear)
    const int sr   = t >> 2;                    // 0..63
    const int slot = t & 3;
    const int key  = (sr & 3) ^ ((sr >> 2) & 3);
    const int gc   = (slot ^ key) * 8;          // inverse-swizzled global col
    const unsigned short* ag = A  + (size_t)(gm0 + sr) * KPITCH + koff + gc;
    const unsigned short* bg = Bt + (size_t)(gn0 + sr) * KPITCH + koff + gc;

    f32x4 acc[4][4];
#pragma unroll
    for (int m = 0; m < 4; ++m)
#pragma unroll
        for (int n = 0; n < 4; ++n)
            acc[m][n] = (f32x4){0.f, 0.f, 0.f, 0.f};

    auto stage = [&](int buf, int kb) {
#pragma unroll
        for (int i = 0; i < 2; ++i)
            gload16(ag + (size_t)(i * 64) * KPITCH + kb, &As[buf][i * 64 + sr][slot * 8]);
#pragma unroll
        for (int i = 0; i < 2; ++i)
            gload16(bg + (size_t)(i * 64) * KPITCH + kb, &Bs[buf][i * 64 + sr][slot * 8]);
    };
    auto compute = [&](int c) {
        short8 af[4], bf[4];
#pragma unroll
        for (int m = 0; m < 4; ++m) af[m] = *(const short8*)&As[c][wm * 64 + m * 16 + fr][csw];
#pragma unroll
        for (int n = 0; n < 4; ++n) bf[n] = *(const short8*)&Bs[c][wn * 64 + n * 16 + fr][csw];
        __builtin_amdgcn_s_setprio(1);
#pragma unroll
        for (int m = 0; m < 4; ++m)
#pragma unroll
            for (int n = 0; n < 4; ++n)
                acc[m][n] = __builtin_amdgcn_mfma_f32_16x16x32_bf16(af[m], bf[n], acc[m][n], 0, 0, 0);
        __builtin_amdgcn_s_setprio(0);
    };

    stage(0, 0);
    stage(1, 32);
    for (int u = 0; u < NT; ++u) {
        if (u + 1 < NT) asm volatile("s_waitcnt vmcnt(4)" ::: "memory");
        else            asm volatile("s_waitcnt vmcnt(0)" ::: "memory");
        __builtin_amdgcn_s_barrier();
        asm volatile("" ::: "memory");
        __builtin_amdgcn_sched_barrier(0);
        compute(u & 1);
        __builtin_amdgcn_sched_barrier(0);
        __builtin_amdgcn_s_barrier();
        asm volatile("" ::: "memory");
        if (u + 2 < NT) stage(u & 1, (u + 2) * 32);
    }

    // epilogue: D mapping col=lane&15, row=(lane>>4)*4+reg
    const int fq = lane >> 4;
    if (MODE == 0) {
        unsigned short* Cb = (unsigned short*)Cbv;
        const int rbase = gm0 & 8191;
        const size_t coloff = (size_t)sel * 1024;
#pragma unroll
        for (int n = 0; n < 4; ++n) {
            const int col = gn0 + wn * 64 + n * 16 + fr;
            const float bv = bias[col];
#pragma unroll
            for (int m = 0; m < 4; ++m) {
                const int row0 = rbase + wm * 64 + m * 16 + fq * 4;
#pragma unroll
                for (int r = 0; r < 4; ++r)
                    Cb[(size_t)(row0 + r) * 2048 + coloff + col] = f2bf(acc[m][n][r] + bv);
            }
        }
    } else {
        float* C = (float*)Cbv + (koff ? 8388608u : 0u);
#pragma unroll
        for (int n = 0; n < 4; ++n) {
            const int col = gn0 + wn * 64 + n * 16 + fr;
            const float bv = bias ? bias[col] : 0.0f;
#pragma unroll
            for (int m = 0; m < 4; ++m) {
                const int row0 = gm0 + wm * 64 + m * 16 + fq * 4;
#pragma unroll
                for (int r = 0; r < 4; ++r)
                    C[(size_t)(row0 + r) * 1024 + col] = acc[m][n][r] + bv;
            }
        }
    }
}

// ---- fused prep: 3 weight transposes (f32 [K][N] -> bf16 [N][K]) + 2 convs ----
__device__ __forceinline__ void wt_tile(
    const float* W, unsigned short* Wt, int K, int N, int bx, int by,
    float (*tile)[33], int t)
{
    const int n0 = bx * 32, k0 = by * 32;
    const int x = t & 31, y = t >> 5;
#pragma unroll
    for (int i = 0; i < 4; ++i)
        tile[y + 8 * i][x] = W[(size_t)(k0 + y + 8 * i) * N + n0 + x];
    __syncthreads();
#pragma unroll
    for (int i = 0; i < 4; ++i)
        Wt[(size_t)(n0 + y + 8 * i) * K + k0 + x] = f2bf(tile[x][y + 8 * i]);
}
__device__ __forceinline__ void conv_chunk(
    const float* in, unsigned short* out, int b, int t)
{
    const size_t i = ((size_t)b * 256 + t) * 8;
    const float4 a = ((const float4*)(in + i))[0];
    const float4 c = ((const float4*)(in + i))[1];
    ushort4 u, v;
    u.x = f2bf(a.x); u.y = f2bf(a.y); u.z = f2bf(a.z); u.w = f2bf(a.w);
    v.x = f2bf(c.x); v.y = f2bf(c.y); v.z = f2bf(c.z); v.w = f2bf(c.w);
    *(ushort4*)(out + i)     = u;
    *(ushort4*)(out + i + 4) = v;
}

__global__ __launch_bounds__(256) void prep_all(
    const float* __restrict__ W_ner, unsigned short* __restrict__ W_nert,
    const float* __restrict__ W_top, unsigned short* __restrict__ W_topt,
    const float* __restrict__ Wg1,   unsigned short* __restrict__ Wg1t,
    const float* __restrict__ ner,   const float* __restrict__ top,
    unsigned short* __restrict__ actb)
{
    __shared__ float tile[32][33];
    int b = blockIdx.x;
    const int t = threadIdx.x;
    if (b < 768)  { wt_tile(W_ner, W_nert, 768, 1024, b % 32, b / 32, tile, t); return; }
    b -= 768;
    if (b < 768)  { wt_tile(W_top, W_topt, 768, 1024, b % 32, b / 32, tile, t); return; }
    b -= 768;
    if (b < 10240) {
        const int z = b / 2048, r = b % 2048;
        wt_tile(Wg1 + (size_t)z * 2097152, Wg1t + (size_t)z * 2097152,
                2048, 1024, r % 32, r / 32, tile, t);
        return;
    }
    b -= 10240;
    if (b < 3072) { conv_chunk(ner, actb, b, t); return; }
    b -= 3072;
    conv_chunk(top, actb + 6291456, b, t);
}

// in-place LN(1024)+ReLU on combined halves (bf16). grid 16384: r=b>>1, half=b&1
__global__ __launch_bounds__(256) void ln_relu_c(
    unsigned short* __restrict__ comb,
    const float* __restrict__ gn, const float* __restrict__ bn,
    const float* __restrict__ gt, const float* __restrict__ btp)
{
    const int b = blockIdx.x, t = threadIdx.x;
    const int r = b >> 1, half = b & 1;
    unsigned short* p = comb + (size_t)r * 2048 + half * 1024 + t * 4;
    ushort4 u = *(const ushort4*)p;
    const float x0 = bf2f(u.x), x1 = bf2f(u.y), x2 = bf2f(u.z), x3 = bf2f(u.w);
    float s1 = x0 + x1 + x2 + x3;
    float s2 = x0 * x0 + x1 * x1 + x2 * x2 + x3 * x3;
#pragma unroll
    for (int off = 32; off > 0; off >>= 1) {
        s1 += __shfl_down(s1, off);
        s2 += __shfl_down(s2, off);
    }
    __shared__ float red[8];
    const int wid = t >> 6;
    if ((t & 63) == 0) { red[wid] = s1; red[4 + wid] = s2; }
    __syncthreads();
    s1 = red[0] + red[1] + red[2] + red[3];
    s2 = red[4] + red[5] + red[6] + red[7];
    const float mean = s1 * (1.0f / 1024.0f);
    const float var = fmaxf(s2 * (1.0f / 1024.0f) - mean * mean, 0.0f);
    const float rstd = rsqrtf(var + 1e-5f);
    const float* G  = half ? gt : gn;
    const float* Be = half ? btp : bn;
    const float4 g  = ((const float4*)G)[t];
    const float4 be = ((const float4*)Be)[t];
    u.x = f2bf(fmaxf((x0 - mean) * rstd * g.x + be.x, 0.0f));
    u.y = f2bf(fmaxf((x1 - mean) * rstd * g.y + be.y, 0.0f));
    u.z = f2bf(fmaxf((x2 - mean) * rstd * g.z + be.z, 0.0f));
    u.w = f2bf(fmaxf((x3 - mean) * rstd * g.w + be.w, 0.0f));
    *(ushort4*)p = u;
}

// Fused: sum K-split f32 partials -> LN(1024)+ReLU (lang) -> gate dots ->
// sigmoid -> scale combined halves -> f32 outputs (overwrites partials).
__global__ __launch_bounds__(256) void ln_gate(
    const float* pa, const float* pb, const unsigned short* comb,
    const float* gg, const float* bgb,
    const float* Wg2, const float* bg2, const int* lang,
    float* outN, float* outT)
{
    const int r = blockIdx.x, t = threadIdx.x;
    const int l = lang[r >> 9];
    const float4 va = ((const float4*)(pa + (size_t)r * 1024))[t];
    const float4 vb = ((const float4*)(pb + (size_t)r * 1024))[t];
    const float x0 = va.x + vb.x, x1 = va.y + vb.y;
    const float x2 = va.z + vb.z, x3 = va.w + vb.w;
    float s1 = x0 + x1 + x2 + x3;
    float s2 = x0 * x0 + x1 * x1 + x2 * x2 + x3 * x3;
#pragma unroll
    for (int off = 32; off > 0; off >>= 1) {
        s1 += __shfl_down(s1, off);
        s2 += __shfl_down(s2, off);
    }
    __shared__ float red[8];
    const int wid = t >> 6;
    if ((t & 63) == 0) { red[wid] = s1; red[4 + wid] = s2; }
    __syncthreads();
    s1 = red[0] + red[1] + red[2] + red[3];
    s2 = red[4] + red[5] + red[6] + red[7];
    const float mean = s1 * (1.0f / 1024.0f);
    const float var = fmaxf(s2 * (1.0f / 1024.0f) - mean * mean, 0.0f);
    const float rstd = rsqrtf(var + 1e-5f);
    const float4 g  = ((const float4*)(gg + l * 1024))[t];
    const float4 be = ((const float4*)(bgb + l * 1024))[t];
    const float h0 = fmaxf((x0 - mean) * rstd * g.x + be.x, 0.0f);
    const float h1 = fmaxf((x1 - mean) * rstd * g.y + be.y, 0.0f);
    const float h2 = fmaxf((x2 - mean) * rstd * g.z + be.z, 0.0f);
    const float h3 = fmaxf((x3 - mean) * rstd * g.w + be.w, 0.0f);
    const float4* W = (const float4*)(Wg2 + (size_t)l * 2048);
    const float4 wa = W[t * 2], wb = W[t * 2 + 1];
    float d0 = h0 * wa.x + h1 * wa.z + h2 * wb.x + h3 * wb.z;
    float d1 = h0 * wa.y + h1 * wa.w + h2 * wb.y + h3 * wb.w;
#pragma unroll
    for (int off = 32; off > 0; off >>= 1) {
        d0 += __shfl_down(d0, off);
        d1 += __shfl_down(d1, off);
    }
    __syncthreads();
    if ((t & 63) == 0) { red[wid] = d0; red[4 + wid] = d1; }
    __syncthreads();
    d0 = red[0] + red[1] + red[2] + red[3] + bg2[l * 2 + 0];
    d1 = red[4] + red[5] + red[6] + red[7] + bg2[l * 2 + 1];
    const float g0 = 1.0f / (1.0f + __expf(-d0));
    const float g1 = 1.0f / (1.0f + __expf(-d1));
    const ushort4 cn = *(const ushort4*)(comb + (size_t)r * 2048 + t * 4);
    const ushort4 ct = *(const ushort4*)(comb + (size_t)r * 2048 + 1024 + t * 4);
    float4 a, b;
    a.x = bf2f(cn.x) * g0; a.y = bf2f(cn.y) * g0; a.z = bf2f(cn.z) * g0; a.w = bf2f(cn.w) * g0;
    b.x = bf2f(ct.x) * g1; b.y = bf2f(ct.y) * g1; b.z = bf2f(ct.z) * g1; b.w = bf2f(ct.w) * g1;
    ((float4*)(outN + (size_t)r * 1024))[t] = a;
    ((float4*)(outT + (size_t)r * 1024))[t] = b;
}

extern "C" void kernel_launch(void* const* d_in, const int* in_sizes, int n_in,
                              void* d_out, int out_size, void* d_ws, size_t ws_size,
                              hipStream_t stream)
{
    const float* ner    = (const float*)d_in[0];
    const float* top    = (const float*)d_in[1];
    const int*   lang   = (const int*)d_in[2];
    const float* W_ner  = (const float*)d_in[3];
    const float* b_ner  = (const float*)d_in[4];
    const float* g_ner  = (const float*)d_in[5];
    const float* be_ner = (const float*)d_in[6];
    const float* W_top  = (const float*)d_in[7];
    const float* b_top  = (const float*)d_in[8];
    const float* g_top  = (const float*)d_in[9];
    const float* be_top = (const float*)d_in[10];
    const float* Wg1    = (const float*)d_in[11];
    const float* bg1    = (const float*)d_in[12];
    const float* gg     = (const float*)d_in[13];
    const float* bgb    = (const float*)d_in[14];
    const float* Wg2    = (const float*)d_in[15];
    const float* bg2    = (const float*)d_in[16];

    float* out  = (float*)d_out;
    float* outN = out;             // final gated_ner; K-split partial 0 before
    float* outT = out + 8388608;   // final gated_topic; weight scratch, partial 1

    // ws layout: combined 32MB | actb 24MB | Wg1t 20MB
    char* ws = (char*)d_ws;
    unsigned short* combined = (unsigned short*)ws;
    unsigned short* actb     = (unsigned short*)(ws + 33554432);
    unsigned short* Wg1t     = (unsigned short*)(ws + 58720256);
    unsigned short* W_nert   = (unsigned short*)outT;     // d_out scratch (dead after GEMM1)
    unsigned short* W_topt   = W_nert + 786432;

    // fused prep: W transposes + activation bf16 converts (one launch)
    prep_all<<<17920, 256, 0, stream>>>(W_ner, W_nert, W_top, W_topt,
                                        Wg1, Wg1t, ner, top, actb);

    // merged shared-transform GEMM: [16384][768] -> combined pre-LN bf16
    gemm_ks<768, 768, 0><<<1024, 256, 0, stream>>>(
        actb, W_nert, W_topt, b_ner, b_top, combined, nullptr);
    ln_relu_c<<<16384, 256, 0, stream>>>(combined, g_ner, be_ner, g_top, be_top);

    // gate GEMM, 2-way K-split, f32 partials into d_out halves
    gemm_ks<2048, 1024, 1><<<1024, 256, 0, stream>>>(
        combined, Wg1t, nullptr, bg1, nullptr, out, lang);

    // fused partial-sum + LN2 + gate + output scaling (overwrites d_out)
    ln_gate<<<8192, 256, 0, stream>>>(outN, outT, combined, gg, bgb, Wg2, bg2,
                                      lang, outN, outT);
}

// Round 9
// 139.889 us; speedup vs baseline: 1.1025x; 1.0923x over previous
//
#include <hip/hip_runtime.h>

typedef __attribute__((ext_vector_type(8))) short short8;
typedef __attribute__((ext_vector_type(4))) float f32x4;

__device__ __forceinline__ float bf2f(unsigned short u) {
    union { unsigned int i; float f; } v; v.i = ((unsigned int)u) << 16; return v.f;
}
__device__ __forceinline__ unsigned short f2bf(float f) {
    union { float f; unsigned int i; } v; v.f = f;
    unsigned int r = v.i + 0x7fffu + ((v.i >> 16) & 1u);  // RNE
    return (unsigned short)(r >> 16);
}
__device__ __forceinline__ void gload16(const unsigned short* g, unsigned short* l) {
    __builtin_amdgcn_global_load_lds(
        (const __attribute__((address_space(1))) unsigned int*)g,
        (__attribute__((address_space(3))) unsigned int*)l, 16, 0, 0);
}

// ---------------------------------------------------------------------------
// R3-verified GEMM: 128x128 tile, BK=64, 4 waves, 2-deep counted-vmcnt(8)
// pipeline, 64KB LDS -> 2 blocks/CU. XOR-swizzled LDS (measured 0 conflicts).
// C[M][1024](bf16) = A[M][K](bf16) @ Bt[1024][K]^T(bf16) + bias.
// MODE 0: merged shared transform (M=16384, sel by row half, out pitch 2048).
// MODE 1: language-selected Wg1 stack (M=8192, out pitch 1024).
// ---------------------------------------------------------------------------
template<int K, int MODE>
__global__ __launch_bounds__(256) void gemm_r3(
    const unsigned short* __restrict__ A,
    const unsigned short* __restrict__ Bta,
    const unsigned short* __restrict__ Btb,
    const float* __restrict__ biasa,
    const float* __restrict__ biasb,
    unsigned short* __restrict__ Cb,
    const int* __restrict__ lang)
{
    __shared__ __align__(16) unsigned short As0[128][64], Bs0[128][64];
    __shared__ __align__(16) unsigned short As1[128][64], Bs1[128][64];

    const int t = threadIdx.x;
    const int nx = gridDim.x;                       // 8
    const int bid = blockIdx.y * nx + blockIdx.x;
    const int cpx = (nx * gridDim.y) >> 3;
    const int swz = (bid & 7) * cpx + (bid >> 3);
    const int gm0 = (swz >> 3) * 128;
    const int gn0 = (swz & 7) * 128;

    const unsigned short* Bt;
    const float* bias;
    int sel = 0;
    if (MODE == 0) {
        sel = gm0 >> 13;
        Bt = sel ? Btb : Bta;
        bias = sel ? biasb : biasa;
    } else {
        const int l = lang[gm0 >> 9];
        Bt = Bta + (size_t)l * ((size_t)K * 1024);
        bias = biasa + l * 1024;
    }

    const int lane = t & 63;
    const int w = t >> 6, wm = w >> 1, wn = w & 1;  // 2x2 waves, 64x64 each
    const int fr = lane & 15, g4 = lane >> 4, f7 = lane & 7;
    const int csw0 = ((0 + g4) ^ f7) * 8;           // swizzled frag cols
    const int csw1 = ((4 + g4) ^ f7) * 8;

    // staging: lane-linear LDS dest (byte offset t*16), pre-swizzled global col
    const int srow = t >> 3;                        // 0..31
    const int swcol = ((t & 7) ^ (srow & 7)) * 8;
    const int lcol = (t & 7) * 8;
    const unsigned short* ag = A  + (size_t)(gm0 + srow) * K + swcol;
    const unsigned short* bg = Bt + (size_t)(gn0 + srow) * K + swcol;

    f32x4 acc[4][4];
#pragma unroll
    for (int m = 0; m < 4; ++m)
#pragma unroll
        for (int n = 0; n < 4; ++n)
            acc[m][n] = (f32x4){0.f, 0.f, 0.f, 0.f};

    auto stage = [&](unsigned short (*As)[64], unsigned short (*Bs)[64], int k0) {
#pragma unroll
        for (int i = 0; i < 4; ++i) {
            gload16(ag + (size_t)(i * 32) * K + k0, &As[i * 32 + srow][lcol]);
            gload16(bg + (size_t)(i * 32) * K + k0, &Bs[i * 32 + srow][lcol]);
        }
    };
    auto compute = [&](const unsigned short (*As)[64], const unsigned short (*Bs)[64]) {
        short8 a0[4], b0[4];
#pragma unroll
        for (int m = 0; m < 4; ++m) a0[m] = *(const short8*)&As[wm * 64 + m * 16 + fr][csw0];
#pragma unroll
        for (int n = 0; n < 4; ++n) b0[n] = *(const short8*)&Bs[wn * 64 + n * 16 + fr][csw0];
#pragma unroll
        for (int m = 0; m < 4; ++m)
#pragma unroll
            for (int n = 0; n < 4; ++n)
                acc[m][n] = __builtin_amdgcn_mfma_f32_16x16x32_bf16(a0[m], b0[n], acc[m][n], 0, 0, 0);
#pragma unroll
        for (int m = 0; m < 4; ++m) a0[m] = *(const short8*)&As[wm * 64 + m * 16 + fr][csw1];
#pragma unroll
        for (int n = 0; n < 4; ++n) b0[n] = *(const short8*)&Bs[wn * 64 + n * 16 + fr][csw1];
#pragma unroll
        for (int m = 0; m < 4; ++m)
#pragma unroll
            for (int n = 0; n < 4; ++n)
                acc[m][n] = __builtin_amdgcn_mfma_f32_16x16x32_bf16(a0[m], b0[n], acc[m][n], 0, 0, 0);
    };

    constexpr int NT = K / 64;           // even (12 or 32)
    stage(As0, Bs0, 0);
    stage(As1, Bs1, 64);

    for (int tt = 0; tt < NT; tt += 2) {
        // ---- even tile (As0/Bs0) ----
        asm volatile("s_waitcnt vmcnt(8)" ::: "memory");
        __builtin_amdgcn_s_barrier();
        asm volatile("" ::: "memory");
        __builtin_amdgcn_sched_barrier(0);
        compute(As0, Bs0);
        __builtin_amdgcn_sched_barrier(0);
        __builtin_amdgcn_s_barrier();
        if (tt + 2 < NT) stage(As0, Bs0, (tt + 2) * 64);
        // ---- odd tile (As1/Bs1) ----
        if (tt + 2 < NT) asm volatile("s_waitcnt vmcnt(8)" ::: "memory");
        else             asm volatile("s_waitcnt vmcnt(0)" ::: "memory");
        __builtin_amdgcn_s_barrier();
        asm volatile("" ::: "memory");
        __builtin_amdgcn_sched_barrier(0);
        compute(As1, Bs1);
        __builtin_amdgcn_sched_barrier(0);
        __builtin_amdgcn_s_barrier();
        if (tt + 3 < NT) stage(As1, Bs1, (tt + 3) * 64);
    }

    // epilogue: D mapping col=lane&15, row=(lane>>4)*4+reg; bf16 store
    const int fq = lane >> 4;
    const size_t pitch  = (MODE == 0) ? 2048 : 1024;
    const size_t coloff = (MODE == 0) ? (size_t)sel * 1024 : 0;
    const int rbase = (MODE == 0) ? (gm0 & 8191) : gm0;
#pragma unroll
    for (int n = 0; n < 4; ++n) {
        const int col = gn0 + wn * 64 + n * 16 + fr;
        const float bv = bias[col];
#pragma unroll
        for (int m = 0; m < 4; ++m) {
            const int row0 = rbase + wm * 64 + m * 16 + fq * 4;
#pragma unroll
            for (int r = 0; r < 4; ++r)
                Cb[(size_t)(row0 + r) * pitch + coloff + col] = f2bf(acc[m][n][r] + bv);
        }
    }
}

// ---- fused prep: 3 weight transposes (f32 [K][N] -> bf16 [N][K]) + 2 convs ----
__device__ __forceinline__ void wt_tile(
    const float* W, unsigned short* Wt, int K, int N, int bx, int by,
    float (*tile)[33], int t)
{
    const int n0 = bx * 32, k0 = by * 32;
    const int x = t & 31, y = t >> 5;
#pragma unroll
    for (int i = 0; i < 4; ++i)
        tile[y + 8 * i][x] = W[(size_t)(k0 + y + 8 * i) * N + n0 + x];
    __syncthreads();
#pragma unroll
    for (int i = 0; i < 4; ++i)
        Wt[(size_t)(n0 + y + 8 * i) * K + k0 + x] = f2bf(tile[x][y + 8 * i]);
}
__device__ __forceinline__ void conv_chunk(
    const float* in, unsigned short* out, int b, int t)
{
    const size_t i = ((size_t)b * 256 + t) * 8;
    const float4 a = ((const float4*)(in + i))[0];
    const float4 c = ((const float4*)(in + i))[1];
    ushort4 u, v;
    u.x = f2bf(a.x); u.y = f2bf(a.y); u.z = f2bf(a.z); u.w = f2bf(a.w);
    v.x = f2bf(c.x); v.y = f2bf(c.y); v.z = f2bf(c.z); v.w = f2bf(c.w);
    *(ushort4*)(out + i)     = u;
    *(ushort4*)(out + i + 4) = v;
}

__global__ __launch_bounds__(256) void prep_all(
    const float* __restrict__ W_ner, unsigned short* __restrict__ W_nert,
    const float* __restrict__ W_top, unsigned short* __restrict__ W_topt,
    const float* __restrict__ Wg1,   unsigned short* __restrict__ Wg1t,
    const float* __restrict__ ner,   const float* __restrict__ top,
    unsigned short* __restrict__ actb)
{
    __shared__ float tile[32][33];
    int b = blockIdx.x;
    const int t = threadIdx.x;
    if (b < 768)  { wt_tile(W_ner, W_nert, 768, 1024, b % 32, b / 32, tile, t); return; }
    b -= 768;
    if (b < 768)  { wt_tile(W_top, W_topt, 768, 1024, b % 32, b / 32, tile, t); return; }
    b -= 768;
    if (b < 10240) {
        const int z = b / 2048, r = b % 2048;
        wt_tile(Wg1 + (size_t)z * 2097152, Wg1t + (size_t)z * 2097152,
                2048, 1024, r % 32, r / 32, tile, t);
        return;
    }
    b -= 10240;
    if (b < 3072) { conv_chunk(ner, actb, b, t); return; }
    b -= 3072;
    conv_chunk(top, actb + 6291456, b, t);
}

// in-place LN(1024)+ReLU on combined halves (bf16). grid 16384: r=b>>1, half=b&1
__global__ __launch_bounds__(256) void ln_relu_c(
    unsigned short* __restrict__ comb,
    const float* __restrict__ gn, const float* __restrict__ bn,
    const float* __restrict__ gt, const float* __restrict__ btp)
{
    const int b = blockIdx.x, t = threadIdx.x;
    const int r = b >> 1, half = b & 1;
    unsigned short* p = comb + (size_t)r * 2048 + half * 1024 + t * 4;
    ushort4 u = *(const ushort4*)p;
    const float x0 = bf2f(u.x), x1 = bf2f(u.y), x2 = bf2f(u.z), x3 = bf2f(u.w);
    float s1 = x0 + x1 + x2 + x3;
    float s2 = x0 * x0 + x1 * x1 + x2 * x2 + x3 * x3;
#pragma unroll
    for (int off = 32; off > 0; off >>= 1) {
        s1 += __shfl_down(s1, off);
        s2 += __shfl_down(s2, off);
    }
    __shared__ float red[8];
    const int wid = t >> 6;
    if ((t & 63) == 0) { red[wid] = s1; red[4 + wid] = s2; }
    __syncthreads();
    s1 = red[0] + red[1] + red[2] + red[3];
    s2 = red[4] + red[5] + red[6] + red[7];
    const float mean = s1 * (1.0f / 1024.0f);
    const float var = fmaxf(s2 * (1.0f / 1024.0f) - mean * mean, 0.0f);
    const float rstd = rsqrtf(var + 1e-5f);
    const float* G  = half ? gt : gn;
    const float* Be = half ? btp : bn;
    const float4 g  = ((const float4*)G)[t];
    const float4 be = ((const float4*)Be)[t];
    u.x = f2bf(fmaxf((x0 - mean) * rstd * g.x + be.x, 0.0f));
    u.y = f2bf(fmaxf((x1 - mean) * rstd * g.y + be.y, 0.0f));
    u.z = f2bf(fmaxf((x2 - mean) * rstd * g.z + be.z, 0.0f));
    u.w = f2bf(fmaxf((x3 - mean) * rstd * g.w + be.w, 0.0f));
    *(ushort4*)p = u;
}

// Fused: LN(1024)+ReLU on preln row (lang gamma/beta) -> gate dots -> sigmoid
// -> scale combined halves -> f32 outputs. One block per row.
__global__ __launch_bounds__(256) void ln_gate(
    const unsigned short* __restrict__ preln, const unsigned short* __restrict__ comb,
    const float* __restrict__ gg, const float* __restrict__ bgb,
    const float* __restrict__ Wg2, const float* __restrict__ bg2,
    const int* __restrict__ lang,
    float* __restrict__ outN, float* __restrict__ outT)
{
    const int r = blockIdx.x, t = threadIdx.x;
    const int l = lang[r >> 9];
    const ushort4 u = *(const ushort4*)(preln + (size_t)r * 1024 + t * 4);
    const float x0 = bf2f(u.x), x1 = bf2f(u.y), x2 = bf2f(u.z), x3 = bf2f(u.w);
    float s1 = x0 + x1 + x2 + x3;
    float s2 = x0 * x0 + x1 * x1 + x2 * x2 + x3 * x3;
#pragma unroll
    for (int off = 32; off > 0; off >>= 1) {
        s1 += __shfl_down(s1, off);
        s2 += __shfl_down(s2, off);
    }
    __shared__ float red[8];
    const int wid = t >> 6;
    if ((t & 63) == 0) { red[wid] = s1; red[4 + wid] = s2; }
    __syncthreads();
    s1 = red[0] + red[1] + red[2] + red[3];
    s2 = red[4] + red[5] + red[6] + red[7];
    const float mean = s1 * (1.0f / 1024.0f);
    const float var = fmaxf(s2 * (1.0f / 1024.0f) - mean * mean, 0.0f);
    const float rstd = rsqrtf(var + 1e-5f);
    const float4 g  = ((const float4*)(gg + l * 1024))[t];
    const float4 be = ((const float4*)(bgb + l * 1024))[t];
    const float h0 = fmaxf((x0 - mean) * rstd * g.x + be.x, 0.0f);
    const float h1 = fmaxf((x1 - mean) * rstd * g.y + be.y, 0.0f);
    const float h2 = fmaxf((x2 - mean) * rstd * g.z + be.z, 0.0f);
    const float h3 = fmaxf((x3 - mean) * rstd * g.w + be.w, 0.0f);
    const float4* W = (const float4*)(Wg2 + (size_t)l * 2048);
    const float4 wa = W[t * 2], wb = W[t * 2 + 1];
    float d0 = h0 * wa.x + h1 * wa.z + h2 * wb.x + h3 * wb.z;
    float d1 = h0 * wa.y + h1 * wa.w + h2 * wb.y + h3 * wb.w;
#pragma unroll
    for (int off = 32; off > 0; off >>= 1) {
        d0 += __shfl_down(d0, off);
        d1 += __shfl_down(d1, off);
    }
    __syncthreads();
    if ((t & 63) == 0) { red[wid] = d0; red[4 + wid] = d1; }
    __syncthreads();
    d0 = red[0] + red[1] + red[2] + red[3] + bg2[l * 2 + 0];
    d1 = red[4] + red[5] + red[6] + red[7] + bg2[l * 2 + 1];
    const float g0 = 1.0f / (1.0f + __expf(-d0));
    const float g1 = 1.0f / (1.0f + __expf(-d1));
    const ushort4 cn = *(const ushort4*)(comb + (size_t)r * 2048 + t * 4);
    const ushort4 ct = *(const ushort4*)(comb + (size_t)r * 2048 + 1024 + t * 4);
    float4 a, b;
    a.x = bf2f(cn.x) * g0; a.y = bf2f(cn.y) * g0; a.z = bf2f(cn.z) * g0; a.w = bf2f(cn.w) * g0;
    b.x = bf2f(ct.x) * g1; b.y = bf2f(ct.y) * g1; b.z = bf2f(ct.z) * g1; b.w = bf2f(ct.w) * g1;
    ((float4*)(outN + (size_t)r * 1024))[t] = a;
    ((float4*)(outT + (size_t)r * 1024))[t] = b;
}

extern "C" void kernel_launch(void* const* d_in, const int* in_sizes, int n_in,
                              void* d_out, int out_size, void* d_ws, size_t ws_size,
                              hipStream_t stream)
{
    const float* ner    = (const float*)d_in[0];
    const float* top    = (const float*)d_in[1];
    const int*   lang   = (const int*)d_in[2];
    const float* W_ner  = (const float*)d_in[3];
    const float* b_ner  = (const float*)d_in[4];
    const float* g_ner  = (const float*)d_in[5];
    const float* be_ner = (const float*)d_in[6];
    const float* W_top  = (const float*)d_in[7];
    const float* b_top  = (const float*)d_in[8];
    const float* g_top  = (const float*)d_in[9];
    const float* be_top = (const float*)d_in[10];
    const float* Wg1    = (const float*)d_in[11];
    const float* bg1    = (const float*)d_in[12];
    const float* gg     = (const float*)d_in[13];
    const float* bgb    = (const float*)d_in[14];
    const float* Wg2    = (const float*)d_in[15];
    const float* bg2    = (const float*)d_in[16];

    float* out  = (float*)d_out;
    float* outN = out;
    float* outT = out + 8388608;

    // ws layout: combined 32MB | actb 24MB (later preln2) | Wg1t 20MB
    char* ws = (char*)d_ws;
    unsigned short* combined = (unsigned short*)ws;
    unsigned short* actb     = (unsigned short*)(ws + 33554432);
    unsigned short* preln2   = (unsigned short*)(ws + 33554432);  // overlays actb (dead)
    unsigned short* Wg1t     = (unsigned short*)(ws + 58720256);
    unsigned short* W_nert   = (unsigned short*)outT;             // d_out scratch
    unsigned short* W_topt   = W_nert + 786432;

    // fused prep: W transposes + activation bf16 converts (one launch)
    prep_all<<<17920, 256, 0, stream>>>(W_ner, W_nert, W_top, W_topt,
                                        Wg1, Wg1t, ner, top, actb);

    // merged shared-transform GEMM: [16384][768] -> combined pre-LN bf16
    gemm_r3<768, 0><<<dim3(8, 128), 256, 0, stream>>>(
        actb, W_nert, W_topt, b_ner, b_top, combined, nullptr);
    ln_relu_c<<<16384, 256, 0, stream>>>(combined, g_ner, be_ner, g_top, be_top);

    // gate GEMM (language-selected): combined @ Wg1t[l] -> preln2 bf16
    gemm_r3<2048, 1><<<dim3(8, 64), 256, 0, stream>>>(
        combined, Wg1t, nullptr, bg1, nullptr, preln2, lang);

    // fused LN2 + gate dots + sigmoid + output scaling
    ln_gate<<<8192, 256, 0, stream>>>(preln2, combined, gg, bgb, Wg2, bg2, lang, outN, outT);
}

// Round 10
// 133.658 us; speedup vs baseline: 1.1539x; 1.0466x over previous
//
#include <hip/hip_runtime.h>

typedef __attribute__((ext_vector_type(8))) short short8;
typedef __attribute__((ext_vector_type(4))) float f32x4;

__device__ __forceinline__ float bf2f(unsigned short u) {
    union { unsigned int i; float f; } v; v.i = ((unsigned int)u) << 16; return v.f;
}
__device__ __forceinline__ unsigned short f2bf(float f) {
    union { float f; unsigned int i; } v; v.f = f;
    unsigned int r = v.i + 0x7fffu + ((v.i >> 16) & 1u);  // RNE
    return (unsigned short)(r >> 16);
}
__device__ __forceinline__ void gload16(const unsigned short* g, unsigned short* l) {
    __builtin_amdgcn_global_load_lds(
        (const __attribute__((address_space(1))) unsigned int*)g,
        (__attribute__((address_space(3))) unsigned int*)l, 16, 0, 0);
}

// ---------------------------------------------------------------------------
// R9-verified GEMM structure, widened to 8 waves/block (512 threads):
// 128x128 tile, BK=64, 2-deep counted-vmcnt pipeline, 64KB LDS ->
// 2 blocks/CU x 8 waves = 16 waves/CU (4/SIMD) for stall overlap.
// Staging identical modulo thread count: lane-linear LDS dest (byte t*16),
// pre-swizzled global col, XOR key (row&7) — measured 0 bank conflicts.
// Wave owns 64m x 32n: wm=w>>2, wn=w&3.
// C[M][1024](bf16) = A[M][K](bf16) @ Bt[1024][K]^T(bf16) + bias.
// MODE 0: merged shared transform (M=16384, sel by row half, out pitch 2048).
// MODE 1: language-selected Wg1 stack (M=8192, out pitch 1024).
// ---------------------------------------------------------------------------
template<int K, int MODE>
__global__ __launch_bounds__(512, 4) void gemm_w8(
    const unsigned short* __restrict__ A,
    const unsigned short* __restrict__ Bta,
    const unsigned short* __restrict__ Btb,
    const float* __restrict__ biasa,
    const float* __restrict__ biasb,
    unsigned short* __restrict__ Cb,
    const int* __restrict__ lang)
{
    __shared__ __align__(16) unsigned short As0[128][64], Bs0[128][64];
    __shared__ __align__(16) unsigned short As1[128][64], Bs1[128][64];

    const int t = threadIdx.x;
    const int nx = gridDim.x;                       // 8
    const int bid = blockIdx.y * nx + blockIdx.x;
    const int cpx = (nx * gridDim.y) >> 3;
    const int swz = (bid & 7) * cpx + (bid >> 3);
    const int gm0 = (swz >> 3) * 128;
    const int gn0 = (swz & 7) * 128;

    const unsigned short* Bt;
    const float* bias;
    int sel = 0;
    if (MODE == 0) {
        sel = gm0 >> 13;
        Bt = sel ? Btb : Bta;
        bias = sel ? biasb : biasa;
    } else {
        const int l = lang[gm0 >> 9];
        Bt = Bta + (size_t)l * ((size_t)K * 1024);
        bias = biasa + l * 1024;
    }

    const int lane = t & 63;
    const int w = t >> 6;
    const int wm = w >> 2, wn = w & 3;              // 2M x 4N waves, 64x32 each
    const int fr = lane & 15, g4 = lane >> 4, f7 = lane & 7;
    const int csw0 = ((0 + g4) ^ f7) * 8;           // swizzled frag cols
    const int csw1 = ((4 + g4) ^ f7) * 8;

    // staging: lane-linear LDS dest (byte offset t*16), pre-swizzled global col
    const int srow = t >> 3;                        // 0..63
    const int swcol = ((t & 7) ^ (srow & 7)) * 8;
    const int lcol = (t & 7) * 8;
    const unsigned short* ag = A  + (size_t)(gm0 + srow) * K + swcol;
    const unsigned short* bg = Bt + (size_t)(gn0 + srow) * K + swcol;

    f32x4 acc[4][2];
#pragma unroll
    for (int m = 0; m < 4; ++m)
#pragma unroll
        for (int n = 0; n < 2; ++n)
            acc[m][n] = (f32x4){0.f, 0.f, 0.f, 0.f};

    auto stage = [&](unsigned short (*As)[64], unsigned short (*Bs)[64], int k0) {
#pragma unroll
        for (int i = 0; i < 2; ++i) {
            gload16(ag + (size_t)(i * 64) * K + k0, &As[i * 64 + srow][lcol]);
            gload16(bg + (size_t)(i * 64) * K + k0, &Bs[i * 64 + srow][lcol]);
        }
    };
    auto compute = [&](const unsigned short (*As)[64], const unsigned short (*Bs)[64]) {
        short8 a0[4], b0[2];
#pragma unroll
        for (int m = 0; m < 4; ++m) a0[m] = *(const short8*)&As[wm * 64 + m * 16 + fr][csw0];
#pragma unroll
        for (int n = 0; n < 2; ++n) b0[n] = *(const short8*)&Bs[wn * 32 + n * 16 + fr][csw0];
        __builtin_amdgcn_s_setprio(1);
#pragma unroll
        for (int m = 0; m < 4; ++m)
#pragma unroll
            for (int n = 0; n < 2; ++n)
                acc[m][n] = __builtin_amdgcn_mfma_f32_16x16x32_bf16(a0[m], b0[n], acc[m][n], 0, 0, 0);
        __builtin_amdgcn_s_setprio(0);
#pragma unroll
        for (int m = 0; m < 4; ++m) a0[m] = *(const short8*)&As[wm * 64 + m * 16 + fr][csw1];
#pragma unroll
        for (int n = 0; n < 2; ++n) b0[n] = *(const short8*)&Bs[wn * 32 + n * 16 + fr][csw1];
        __builtin_amdgcn_s_setprio(1);
#pragma unroll
        for (int m = 0; m < 4; ++m)
#pragma unroll
            for (int n = 0; n < 2; ++n)
                acc[m][n] = __builtin_amdgcn_mfma_f32_16x16x32_bf16(a0[m], b0[n], acc[m][n], 0, 0, 0);
        __builtin_amdgcn_s_setprio(0);
    };

    constexpr int NT = K / 64;           // even (12 or 32)
    stage(As0, Bs0, 0);
    stage(As1, Bs1, 64);

    for (int tt = 0; tt < NT; tt += 2) {
        // ---- even tile (As0/Bs0): 4 loads/thread/tile -> vmcnt(4) = 1 tile ----
        asm volatile("s_waitcnt vmcnt(4)" ::: "memory");
        __builtin_amdgcn_s_barrier();
        asm volatile("" ::: "memory");
        __builtin_amdgcn_sched_barrier(0);
        compute(As0, Bs0);
        __builtin_amdgcn_sched_barrier(0);
        __builtin_amdgcn_s_barrier();
        if (tt + 2 < NT) stage(As0, Bs0, (tt + 2) * 64);
        // ---- odd tile (As1/Bs1) ----
        if (tt + 2 < NT) asm volatile("s_waitcnt vmcnt(4)" ::: "memory");
        else             asm volatile("s_waitcnt vmcnt(0)" ::: "memory");
        __builtin_amdgcn_s_barrier();
        asm volatile("" ::: "memory");
        __builtin_amdgcn_sched_barrier(0);
        compute(As1, Bs1);
        __builtin_amdgcn_sched_barrier(0);
        __builtin_amdgcn_s_barrier();
        if (tt + 3 < NT) stage(As1, Bs1, (tt + 3) * 64);
    }

    // epilogue: D mapping col=lane&15, row=(lane>>4)*4+reg; bf16 store
    const int fq = lane >> 4;
    const size_t pitch  = (MODE == 0) ? 2048 : 1024;
    const size_t coloff = (MODE == 0) ? (size_t)sel * 1024 : 0;
    const int rbase = (MODE == 0) ? (gm0 & 8191) : gm0;
#pragma unroll
    for (int n = 0; n < 2; ++n) {
        const int col = gn0 + wn * 32 + n * 16 + fr;
        const float bv = bias[col];
#pragma unroll
        for (int m = 0; m < 4; ++m) {
            const int row0 = rbase + wm * 64 + m * 16 + fq * 4;
#pragma unroll
            for (int r = 0; r < 4; ++r)
                Cb[(size_t)(row0 + r) * pitch + coloff + col] = f2bf(acc[m][n][r] + bv);
        }
    }
}

// ---- fused prep: 3 weight transposes (f32 [K][N] -> bf16 [N][K]) + 2 convs ----
__device__ __forceinline__ void wt_tile(
    const float* W, unsigned short* Wt, int K, int N, int bx, int by,
    float (*tile)[33], int t)
{
    const int n0 = bx * 32, k0 = by * 32;
    const int x = t & 31, y = t >> 5;
#pragma unroll
    for (int i = 0; i < 4; ++i)
        tile[y + 8 * i][x] = W[(size_t)(k0 + y + 8 * i) * N + n0 + x];
    __syncthreads();
#pragma unroll
    for (int i = 0; i < 4; ++i)
        Wt[(size_t)(n0 + y + 8 * i) * K + k0 + x] = f2bf(tile[x][y + 8 * i]);
}
__device__ __forceinline__ void conv_chunk(
    const float* in, unsigned short* out, int b, int t)
{
    const size_t i = ((size_t)b * 256 + t) * 8;
    const float4 a = ((const float4*)(in + i))[0];
    const float4 c = ((const float4*)(in + i))[1];
    ushort4 u, v;
    u.x = f2bf(a.x); u.y = f2bf(a.y); u.z = f2bf(a.z); u.w = f2bf(a.w);
    v.x = f2bf(c.x); v.y = f2bf(c.y); v.z = f2bf(c.z); v.w = f2bf(c.w);
    *(ushort4*)(out + i)     = u;
    *(ushort4*)(out + i + 4) = v;
}

__global__ __launch_bounds__(256) void prep_all(
    const float* __restrict__ W_ner, unsigned short* __restrict__ W_nert,
    const float* __restrict__ W_top, unsigned short* __restrict__ W_topt,
    const float* __restrict__ Wg1,   unsigned short* __restrict__ Wg1t,
    const float* __restrict__ ner,   const float* __restrict__ top,
    unsigned short* __restrict__ actb)
{
    __shared__ float tile[32][33];
    int b = blockIdx.x;
    const int t = threadIdx.x;
    if (b < 768)  { wt_tile(W_ner, W_nert, 768, 1024, b % 32, b / 32, tile, t); return; }
    b -= 768;
    if (b < 768)  { wt_tile(W_top, W_topt, 768, 1024, b % 32, b / 32, tile, t); return; }
    b -= 768;
    if (b < 10240) {
        const int z = b / 2048, r = b % 2048;
        wt_tile(Wg1 + (size_t)z * 2097152, Wg1t + (size_t)z * 2097152,
                2048, 1024, r % 32, r / 32, tile, t);
        return;
    }
    b -= 10240;
    if (b < 3072) { conv_chunk(ner, actb, b, t); return; }
    b -= 3072;
    conv_chunk(top, actb + 6291456, b, t);
}

// in-place LN(1024)+ReLU on combined halves (bf16). grid 16384: r=b>>1, half=b&1
__global__ __launch_bounds__(256) void ln_relu_c(
    unsigned short* __restrict__ comb,
    const float* __restrict__ gn, const float* __restrict__ bn,
    const float* __restrict__ gt, const float* __restrict__ btp)
{
    const int b = blockIdx.x, t = threadIdx.x;
    const int r = b >> 1, half = b & 1;
    unsigned short* p = comb + (size_t)r * 2048 + half * 1024 + t * 4;
    ushort4 u = *(const ushort4*)p;
    const float x0 = bf2f(u.x), x1 = bf2f(u.y), x2 = bf2f(u.z), x3 = bf2f(u.w);
    float s1 = x0 + x1 + x2 + x3;
    float s2 = x0 * x0 + x1 * x1 + x2 * x2 + x3 * x3;
#pragma unroll
    for (int off = 32; off > 0; off >>= 1) {
        s1 += __shfl_down(s1, off);
        s2 += __shfl_down(s2, off);
    }
    __shared__ float red[8];
    const int wid = t >> 6;
    if ((t & 63) == 0) { red[wid] = s1; red[4 + wid] = s2; }
    __syncthreads();
    s1 = red[0] + red[1] + red[2] + red[3];
    s2 = red[4] + red[5] + red[6] + red[7];
    const float mean = s1 * (1.0f / 1024.0f);
    const float var = fmaxf(s2 * (1.0f / 1024.0f) - mean * mean, 0.0f);
    const float rstd = rsqrtf(var + 1e-5f);
    const float* G  = half ? gt : gn;
    const float* Be = half ? btp : bn;
    const float4 g  = ((const float4*)G)[t];
    const float4 be = ((const float4*)Be)[t];
    u.x = f2bf(fmaxf((x0 - mean) * rstd * g.x + be.x, 0.0f));
    u.y = f2bf(fmaxf((x1 - mean) * rstd * g.y + be.y, 0.0f));
    u.z = f2bf(fmaxf((x2 - mean) * rstd * g.z + be.z, 0.0f));
    u.w = f2bf(fmaxf((x3 - mean) * rstd * g.w + be.w, 0.0f));
    *(ushort4*)p = u;
}

// Fused: LN(1024)+ReLU on preln row (lang gamma/beta) -> gate dots -> sigmoid
// -> scale combined halves -> f32 outputs. One block per row.
__global__ __launch_bounds__(256) void ln_gate(
    const unsigned short* __restrict__ preln, const unsigned short* __restrict__ comb,
    const float* __restrict__ gg, const float* __restrict__ bgb,
    const float* __restrict__ Wg2, const float* __restrict__ bg2,
    const int* __restrict__ lang,
    float* __restrict__ outN, float* __restrict__ outT)
{
    const int r = blockIdx.x, t = threadIdx.x;
    const int l = lang[r >> 9];
    const ushort4 u = *(const ushort4*)(preln + (size_t)r * 1024 + t * 4);
    const float x0 = bf2f(u.x), x1 = bf2f(u.y), x2 = bf2f(u.z), x3 = bf2f(u.w);
    float s1 = x0 + x1 + x2 + x3;
    float s2 = x0 * x0 + x1 * x1 + x2 * x2 + x3 * x3;
#pragma unroll
    for (int off = 32; off > 0; off >>= 1) {
        s1 += __shfl_down(s1, off);
        s2 += __shfl_down(s2, off);
    }
    __shared__ float red[8];
    const int wid = t >> 6;
    if ((t & 63) == 0) { red[wid] = s1; red[4 + wid] = s2; }
    __syncthreads();
    s1 = red[0] + red[1] + red[2] + red[3];
    s2 = red[4] + red[5] + red[6] + red[7];
    const float mean = s1 * (1.0f / 1024.0f);
    const float var = fmaxf(s2 * (1.0f / 1024.0f) - mean * mean, 0.0f);
    const float rstd = rsqrtf(var + 1e-5f);
    const float4 g  = ((const float4*)(gg + l * 1024))[t];
    const float4 be = ((const float4*)(bgb + l * 1024))[t];
    const float h0 = fmaxf((x0 - mean) * rstd * g.x + be.x, 0.0f);
    const float h1 = fmaxf((x1 - mean) * rstd * g.y + be.y, 0.0f);
    const float h2 = fmaxf((x2 - mean) * rstd * g.z + be.z, 0.0f);
    const float h3 = fmaxf((x3 - mean) * rstd * g.w + be.w, 0.0f);
    const float4* W = (const float4*)(Wg2 + (size_t)l * 2048);
    const float4 wa = W[t * 2], wb = W[t * 2 + 1];
    float d0 = h0 * wa.x + h1 * wa.z + h2 * wb.x + h3 * wb.z;
    float d1 = h0 * wa.y + h1 * wa.w + h2 * wb.y + h3 * wb.w;
#pragma unroll
    for (int off = 32; off > 0; off >>= 1) {
        d0 += __shfl_down(d0, off);
        d1 += __shfl_down(d1, off);
    }
    __syncthreads();
    if ((t & 63) == 0) { red[wid] = d0; red[4 + wid] = d1; }
    __syncthreads();
    d0 = red[0] + red[1] + red[2] + red[3] + bg2[l * 2 + 0];
    d1 = red[4] + red[5] + red[6] + red[7] + bg2[l * 2 + 1];
    const float g0 = 1.0f / (1.0f + __expf(-d0));
    const float g1 = 1.0f / (1.0f + __expf(-d1));
    const ushort4 cn = *(const ushort4*)(comb + (size_t)r * 2048 + t * 4);
    const ushort4 ct = *(const ushort4*)(comb + (size_t)r * 2048 + 1024 + t * 4);
    float4 a, b;
    a.x = bf2f(cn.x) * g0; a.y = bf2f(cn.y) * g0; a.z = bf2f(cn.z) * g0; a.w = bf2f(cn.w) * g0;
    b.x = bf2f(ct.x) * g1; b.y = bf2f(ct.y) * g1; b.z = bf2f(ct.z) * g1; b.w = bf2f(ct.w) * g1;
    ((float4*)(outN + (size_t)r * 1024))[t] = a;
    ((float4*)(outT + (size_t)r * 1024))[t] = b;
}

extern "C" void kernel_launch(void* const* d_in, const int* in_sizes, int n_in,
                              void* d_out, int out_size, void* d_ws, size_t ws_size,
                              hipStream_t stream)
{
    const float* ner    = (const float*)d_in[0];
    const float* top    = (const float*)d_in[1];
    const int*   lang   = (const int*)d_in[2];
    const float* W_ner  = (const float*)d_in[3];
    const float* b_ner  = (const float*)d_in[4];
    const float* g_ner  = (const float*)d_in[5];
    const float* be_ner = (const float*)d_in[6];
    const float* W_top  = (const float*)d_in[7];
    const float* b_top  = (const float*)d_in[8];
    const float* g_top  = (const float*)d_in[9];
    const float* be_top = (const float*)d_in[10];
    const float* Wg1    = (const float*)d_in[11];
    const float* bg1    = (const float*)d_in[12];
    const float* gg     = (const float*)d_in[13];
    const float* bgb    = (const float*)d_in[14];
    const float* Wg2    = (const float*)d_in[15];
    const float* bg2    = (const float*)d_in[16];

    float* out  = (float*)d_out;
    float* outN = out;
    float* outT = out + 8388608;

    // ws layout: combined 32MB | actb 24MB (later preln2) | Wg1t 20MB
    char* ws = (char*)d_ws;
    unsigned short* combined = (unsigned short*)ws;
    unsigned short* actb     = (unsigned short*)(ws + 33554432);
    unsigned short* preln2   = (unsigned short*)(ws + 33554432);  // overlays actb (dead)
    unsigned short* Wg1t     = (unsigned short*)(ws + 58720256);
    unsigned short* W_nert   = (unsigned short*)outT;             // d_out scratch
    unsigned short* W_topt   = W_nert + 786432;

    // fused prep: W transposes + activation bf16 converts (one launch)
    prep_all<<<17920, 256, 0, stream>>>(W_ner, W_nert, W_top, W_topt,
                                        Wg1, Wg1t, ner, top, actb);

    // merged shared-transform GEMM: [16384][768] -> combined pre-LN bf16
    gemm_w8<768, 0><<<dim3(8, 128), 512, 0, stream>>>(
        actb, W_nert, W_topt, b_ner, b_top, combined, nullptr);
    ln_relu_c<<<16384, 256, 0, stream>>>(combined, g_ner, be_ner, g_top, be_top);

    // gate GEMM (language-selected): combined @ Wg1t[l] -> preln2 bf16
    gemm_w8<2048, 1><<<dim3(8, 64), 512, 0, stream>>>(
        combined, Wg1t, nullptr, bg1, nullptr, preln2, lang);

    // fused LN2 + gate dots + sigmoid + output scaling
    ln_gate<<<8192, 256, 0, stream>>>(preln2, combined, gg, bgb, Wg2, bg2, lang, outN, outT);
}